// Round 8
// baseline (352.225 us; speedup 1.0000x reference)
//
#include <hip/hip_runtime.h>
#include <cstdint>

// LatentFactorPooling on MI355X.
// x: (64,256,64,44) fp32, basis: (4,16,256) fp32.
// out: tokens (64,256,64) fp32 then pres (64,64) fp32.
//
// Workspace layout (floats):
//   lbn_ws     [0,16384)             normalized basis, [g][c][k]
//   invden_ws  [16384,20480)         1/max(sum_p supp,1e-6) per (s,k)
//   presraw    [20480,24576)         unnormalized presence per (s,k)
//   supp_kp    [24576,2908160)       UNPOOLED rawdot partial half0 [s][p][k]
//   supp_pk    [2908160,5791744)     supp, [s][p][k]  (tokens kernel)
//                                    ALIASED: UNPOOLED rawdot partial half1 [s][p][k]
// sq/pw2 partials ([s][half][p][2], 720896 floats) are staged in the OUT
// tokens region (1048576 floats), which k_tokens fully overwrites later.

#define C_ 256
#define W_ 44
#define P_ 704          // 16*44 positions per stripe
#define CH_STRIDE 2816  // 64*44
#define NB_STRIDE 720896 // 256*2816
#define TOPK_ 88
#define GATE_ 0.05f
#define EPS_ 1e-6f

// DPP wave-wide shifts: lane i <- lane i-1 (shr) / i+1 (shl), bound_ctrl
// zero-fills the edge lane. VALU pipe.
#define DPP_WAVE_SHL1 0x130
#define DPP_WAVE_SHR1 0x138
__device__ __forceinline__ float dpp_from_left(float v) {   // lane l gets v[l-1], lane0 -> 0
  return __int_as_float(__builtin_amdgcn_update_dpp(
      0, __float_as_int(v), DPP_WAVE_SHR1, 0xF, 0xF, true));
}
__device__ __forceinline__ float dpp_from_right(float v) {  // lane l gets v[l+1], lane63 -> 0
  return __int_as_float(__builtin_amdgcn_update_dpp(
      0, __float_as_int(v), DPP_WAVE_SHL1, 0xF, 0xF, true));
}

// ---------------- kernel A: normalize latent basis ----------------
__global__ __launch_bounds__(256) void k_norm_basis(const float* __restrict__ lb,
                                                    float* __restrict__ lbn) {
  int gk = blockIdx.x;           // g*16+k
  int t = threadIdx.x;           // channel
  float v = lb[gk * 256 + t];
  float ss = v * v;
  #pragma unroll
  for (int off = 32; off >= 1; off >>= 1) ss += __shfl_xor(ss, off);
  __shared__ float red[4];
  if ((t & 63) == 0) red[t >> 6] = ss;
  __syncthreads();
  float tot = red[0] + red[1] + red[2] + red[3];
  float scale = 1.f / fmaxf(sqrtf(tot), 1e-12f);
  int g = gk >> 4, k = gk & 15;
  lbn[((g * 256 + t) << 4) + k] = v * scale;   // [g][c][k]
}

// ---------------- kernel B1: routing dot-products, 4-rows-per-wave -----------
// Round-11 theory: all five prior variants (105-112us) shared ONE invariant —
// logical L2/L3 read traffic (3 row-loads per position = 553 MB, x is
// L3-resident; 553MB/105us = 5.3 TB/s = Infinity-Cache delivery ceiling).
// Instruction count (-25%), DS removal, and occupancy changes all moved
// nothing -> the kernel is L3-BW-bound. Fix: each wave owns 4 ROWS
// (rawdot[4][16] accumulators) and loads 6 rows/channel (4 owned + 2 halo)
// instead of 4 waves x 3 = 12 -> logical reads drop 3x -> 1.5x (553->277MB).
// Basis scalar-loads amortize 4x. Halo masks are wave-uniform (wq>0 / wq<3).
// Per-position FMA order unchanged -> bit-identical outputs.
#define LOAD6(R, cbase)                                                \
  { const size_t o_ = (size_t)(cbase) * CH_STRIDE;                     \
    R[0] = rp0[o_]; R[1] = rp1[o_]; R[2] = rp2[o_];                    \
    R[3] = rp3[o_]; R[4] = rp4[o_]; R[5] = rp5[o_]; }

#define CONS6(R, cbase)                                                \
  { const int co_ = __builtin_amdgcn_readfirstlane((cbase) << 4);      \
    const float4* wp4 = (const float4*)(lbb + co_);                    \
    float4 w0 = wp4[0], w1 = wp4[1], w2 = wp4[2], w3 = wp4[3];         \
    _Pragma("unroll")                                                  \
    for (int j_ = 0; j_ < 4; j_++) {                                   \
      float a  = act ? R[j_ + 1] : 0.f;                                \
      bool hmj = (j_ > 0) || hmw;                                      \
      bool hpj = (j_ < 3) || hpw;                                      \
      float am_ = (act && hmj) ? R[j_] : 0.f;                          \
      float ap_ = (act && hpj) ? R[j_ + 2] : 0.f;                      \
      float vs = am_ + a + ap_;                                        \
      float lf = dpp_from_left(vs);                                    \
      float rt = dpp_from_right(vs);                                   \
      float win = lf + vs + rt;                                        \
      pw2[j_] = fmaf(win, win, pw2[j_]);                               \
      sq[j_]  = fmaf(a, a, sq[j_]);                                    \
      float* rd = &rawdot[j_][0];                                      \
      rd[0]  = fmaf(a, w0.x, rd[0]);  rd[1]  = fmaf(a, w0.y, rd[1]);   \
      rd[2]  = fmaf(a, w0.z, rd[2]);  rd[3]  = fmaf(a, w0.w, rd[3]);   \
      rd[4]  = fmaf(a, w1.x, rd[4]);  rd[5]  = fmaf(a, w1.y, rd[5]);   \
      rd[6]  = fmaf(a, w1.z, rd[6]);  rd[7]  = fmaf(a, w1.w, rd[7]);   \
      rd[8]  = fmaf(a, w2.x, rd[8]);  rd[9]  = fmaf(a, w2.y, rd[9]);   \
      rd[10] = fmaf(a, w2.z, rd[10]); rd[11] = fmaf(a, w2.w, rd[11]);  \
      rd[12] = fmaf(a, w3.x, rd[12]); rd[13] = fmaf(a, w3.y, rd[13]);  \
      rd[14] = fmaf(a, w3.z, rd[14]); rd[15] = fmaf(a, w3.w, rd[15]);  \
    } }

__global__ __launch_bounds__(256, 2) void k_route_dot(const float* __restrict__ x,
                                                      const float* __restrict__ lbn,
                                                      float* __restrict__ pd0,   // supp_kp region
                                                      float* __restrict__ pd1,   // supp_pk region
                                                      float* __restrict__ sqpw) { // out region scratch
  const int tid = threadIdx.x;
  const int wq = tid >> 6;         // wave in block: 0..3 -> rows 4wq..4wq+3
  const int l = tid & 63;          // col
  const bool act = (l < 44);
  const int bid = blockIdx.x;
  const int s = bid >> 1, half = bid & 1;
  const int n = s >> 2, g = s & 3;
  const int rbase = wq * 4;        // first owned row
  const bool hmw = (wq > 0);       // row rbase has an upper neighbor
  const bool hpw = (wq < 3);       // row rbase+3 has a lower neighbor

  const int lsafe = act ? l : 0;   // address clamp
  const float* xc = x + (size_t)n * NB_STRIDE + (size_t)(half * 128) * CH_STRIDE
                      + g * 704 + lsafe;
  // 6 source rows rbase-1 .. rbase+4, addresses clamped to [0,15] (masked at use)
  const float* rp0 = xc + ((rbase - 1 < 0)  ? 0  : rbase - 1) * 44;
  const float* rp1 = xc + (rbase + 0) * 44;
  const float* rp2 = xc + (rbase + 1) * 44;
  const float* rp3 = xc + (rbase + 2) * 44;
  const float* rp4 = xc + (rbase + 3) * 44;
  const float* rp5 = xc + ((rbase + 4 > 15) ? 15 : rbase + 4) * 44;

  // wave-uniform basis base for this (g, half): 128ch x 16k slice
  const float* lbb = lbn + (g << 12) + (half << 11);

  float rawdot[4][16];
  #pragma unroll
  for (int j = 0; j < 4; j++)
    #pragma unroll
    for (int k = 0; k < 16; k++) rawdot[j][k] = 0.f;
  float sq[4] = {0.f, 0.f, 0.f, 0.f};
  float pw2[4] = {0.f, 0.f, 0.f, 0.f};

  float A[6], B[6];
  LOAD6(A, 0)
  for (int c = 0; c < 128; c += 2) {
    LOAD6(B, c + 1)
    CONS6(A, c)
    if (c + 2 < 128) { LOAD6(A, c + 2) }
    CONS6(B, c + 1)
  }

  // epilogue: write UNPOOLED partial rawdot + (sq,pw2) partials, 4 rows
  if (act) {
    #pragma unroll
    for (int j = 0; j < 4; j++) {
      const int p = (rbase + j) * 44 + l;
      float* dst = (half ? pd1 : pd0) + (size_t)s * 11264 + p * 16;
      #pragma unroll
      for (int kq = 0; kq < 4; kq++)
        ((float4*)dst)[kq] = make_float4(rawdot[j][kq*4+0], rawdot[j][kq*4+1],
                                         rawdot[j][kq*4+2], rawdot[j][kq*4+3]);
      *(float2*)(sqpw + ((size_t)(s * 2 + half) * 704 + p) * 2) =
          make_float2(sq[j], pw2[j]);
    }
  }
}

// ---------------- kernel B2: combine, pool, softmax, supp, invden + FUSED topk ----
__global__ __launch_bounds__(1024) void k_route_fin(const float* __restrict__ pd0,
                                                    const float* __restrict__ pd1,
                                                    const float* __restrict__ sqpw,
                                                    float* __restrict__ supp_pk,
                                                    float* __restrict__ invden_ws,
                                                    float* __restrict__ presraw) {
  __shared__ float rsl[11264];      // rawdot [k][704], then supp [k][704]; 44 KB
  __shared__ uint32_t hist_l[16 * 256]; // per-wave radix histograms, 16 KB
  __shared__ float redA[16];
  __shared__ float redB[16];
  __shared__ float redM[2];
  __shared__ float red2[16 * 16];

  const int tid = threadIdx.x;
  const int w = tid >> 6;
  const int l = tid & 63;
  const bool act = (l < 44);
  const int s = blockIdx.x;
  const int p = w * 44 + l;

  float sq = 0.f, pw2 = 0.f;
  if (act) {
    const float4* a0 = (const float4*)(pd0 + (size_t)s * 11264 + p * 16);
    const float4* a1 = (const float4*)(pd1 + (size_t)s * 11264 + p * 16);
    #pragma unroll
    for (int kq = 0; kq < 4; kq++) {
      float4 u = a0[kq], v = a1[kq];
      rsl[(kq*4+0) * 704 + p] = u.x + v.x;
      rsl[(kq*4+1) * 704 + p] = u.y + v.y;
      rsl[(kq*4+2) * 704 + p] = u.z + v.z;
      rsl[(kq*4+3) * 704 + p] = u.w + v.w;
    }
    float2 s0 = *(const float2*)(sqpw + ((size_t)(s * 2 + 0) * 704 + p) * 2);
    float2 s1 = *(const float2*)(sqpw + ((size_t)(s * 2 + 1) * 704 + p) * 2);
    sq = s0.x + s1.x; pw2 = s0.y + s1.y;
  }
  __syncthreads();   // rsl ready

  // 3x3 pool of combined rawdot (linearity)
  float pd[16];
  #pragma unroll
  for (int k = 0; k < 16; k++) pd[k] = 0.f;
  if (act) {
    #pragma unroll
    for (int dy = -1; dy <= 1; dy++) {
      int yy = w + dy;
      if (yy < 0 || yy > 15) continue;
      #pragma unroll
      for (int dx = -1; dx <= 1; dx++) {
        int xx = l + dx;
        if (xx < 0 || xx > 43) continue;
        int pp = yy * 44 + xx;
        #pragma unroll
        for (int k = 0; k < 16; k++) pd[k] += rsl[k * 704 + pp];
      }
    }
  }

  // stripe-wide energy max
  float e_raw = sq * (1.f / 256.f);            // inactive lanes: 0
  float m = e_raw;
  #pragma unroll
  for (int off = 32; off >= 1; off >>= 1) m = fmaxf(m, __shfl_xor(m, off));
  if (l == 0) redA[w] = m;
  __syncthreads();                             // (also: all rsl pool-reads done)
  if (tid == 0) {
    float mm = redA[0];
    for (int w2 = 1; w2 < 16; w2++) mm = fmaxf(mm, redA[w2]);
    redM[0] = mm;
  }
  __syncthreads();
  float M = fmaxf(redM[0], EPS_);
  float e = e_raw / M;
  float am = (e > GATE_) ? 1.f : 0.f;
  float fb = (e_raw > 0.f) ? 1.f : 0.f;
  float a = am;
  #pragma unroll
  for (int off = 32; off >= 1; off >>= 1) a += __shfl_xor(a, off);
  if (l == 0) redB[w] = a;
  __syncthreads();
  if (tid == 0) {
    float sm = 0.f;
    for (int w2 = 0; w2 < 16; w2++) sm += redB[w2];
    redM[1] = sm;
  }
  __syncthreads();
  if (redM[1] <= 0.f) am = fb;

  float pnorm = sqrtf(pw2) * (1.f / 9.f);      // ||pooled||
  float invn = 1.f / fmaxf(pnorm, 1e-12f);
  float scl = invn * (8.f / 9.f);              // /9 pool, /0.125 temp
  float li[16];
  float mx = -1e30f;
  #pragma unroll
  for (int k = 0; k < 16; k++) { li[k] = pd[k] * scl; mx = fmaxf(mx, li[k]); }
  float ssum = 0.f;
  #pragma unroll
  for (int k = 0; k < 16; k++) { li[k] = __expf(li[k] - mx); ssum += li[k]; }
  float rs2 = am / ssum;
  float supp[16];
  #pragma unroll
  for (int k = 0; k < 16; k++) supp[k] = li[k] * rs2;

  // global supp in [p][k] layout for k_tokens
  if (act) {
    float* spk = supp_pk + ((size_t)s * 704 + p) * 16;
    #pragma unroll
    for (int kq = 0; kq < 4; kq++)
      ((float4*)spk)[kq] = make_float4(supp[kq*4+0], supp[kq*4+1],
                                       supp[kq*4+2], supp[kq*4+3]);
  }

  // per-k denominators (inactive lanes contribute 0)
  #pragma unroll
  for (int k = 0; k < 16; k++) {
    float v2 = act ? supp[k] : 0.f;
    #pragma unroll
    for (int off = 32; off >= 1; off >>= 1) v2 += __shfl_xor(v2, off);
    if (l == 0) red2[w * 16 + k] = v2;
  }
  __syncthreads();
  if (tid < 16) {
    float den = 0.f;
    for (int w2 = 0; w2 < 16; w2++) den += red2[w2 * 16 + tid];
    invden_ws[s * 16 + tid] = 1.f / fmaxf(den, EPS_);
  }

  // ---- fused exact top-88 mean (per-wave radix select) ----
  if (act) {
    #pragma unroll
    for (int k = 0; k < 16; k++) rsl[k * 704 + p] = supp[k];
  }
  __syncthreads();   // supp in LDS visible to all waves

  {
    const int k = w;               // wave w owns latent k
    uint32_t key[11];
    #pragma unroll
    for (int j = 0; j < 11; j++)
      key[j] = __float_as_uint(rsl[k * 704 + l + 64 * j]);  // supp>=0 -> monotone bits
    uint32_t* h = &hist_l[w * 256];
    uint32_t prefix = 0, remaining = TOPK_;
    #pragma unroll
    for (int b = 3; b >= 0; b--) {
      const int shift = b * 8;
      *(uint4*)&h[l * 4] = make_uint4(0u, 0u, 0u, 0u);
      uint32_t mhi = (b == 3) ? 0u : (0xFFFFFFFFu << (shift + 8));
      #pragma unroll
      for (int j = 0; j < 11; j++)
        if ((key[j] & mhi) == (prefix & mhi))
          atomicAdd(&h[(key[j] >> shift) & 255u], 1u);
      uint4 bn = *(uint4*)&h[l * 4];
      uint32_t T = bn.x + bn.y + bn.z + bn.w;
      uint32_t inc = T;
      #pragma unroll
      for (int off = 1; off < 64; off <<= 1) {
        uint32_t o = (uint32_t)__shfl_down((int)inc, off);
        if (l + off < 64) inc += o;
      }                              // inc = sum over lanes >= l
      uint32_t excl = inc - T;       // lanes > l
      uint32_t g3 = excl + bn.w, g2 = g3 + bn.z, g1 = g2 + bn.y, g0 = g1 + bn.x;
      uint32_t pk = 0u;
      if (g0 >= remaining && g1 < remaining) pk = ((uint32_t)(4*l+0) << 16) | (remaining - g1);
      if (g1 >= remaining && g2 < remaining) pk = ((uint32_t)(4*l+1) << 16) | (remaining - g2);
      if (g2 >= remaining && g3 < remaining) pk = ((uint32_t)(4*l+2) << 16) | (remaining - g3);
      if (g3 >= remaining && excl < remaining) pk = ((uint32_t)(4*l+3) << 16) | (remaining - excl);
      #pragma unroll
      for (int off = 32; off >= 1; off >>= 1) pk |= (uint32_t)__shfl_xor((int)pk, off);
      prefix |= ((pk >> 16) & 255u) << shift;
      remaining = pk & 0xFFFFu;
    }
    float tf = __uint_as_float(prefix);
    float sgt = 0.f; uint32_t cgt = 0u;
    #pragma unroll
    for (int j = 0; j < 11; j++)
      if (key[j] > prefix) { sgt += __uint_as_float(key[j]); cgt++; }
    #pragma unroll
    for (int off = 32; off >= 1; off >>= 1) {
      sgt += __shfl_xor(sgt, off);
      cgt += (uint32_t)__shfl_xor((int)cgt, off);
    }
    if (l == 0)
      presraw[s * 16 + k] = (sgt + (float)(TOPK_ - cgt) * tf) * (1.f / (float)TOPK_);
  }
}

// ---------------- kernel 3: tokens GEMM, channel-split (2 blocks/stripe) ----------------
__global__ __launch_bounds__(512, 4) void k_tokens(const float* __restrict__ x,
                                                   const float* __restrict__ supp_pk,
                                                   const float* __restrict__ invden,
                                                   float* __restrict__ out) {
  __shared__ float xl[4096];   // 128ch x 32pos; reused for quarter-reduce
  const int tid = threadIdx.x;
  const int bid = blockIdx.x;
  const int s = bid >> 1, chalf = bid & 1;
  const int n = s >> 2, g = s & 3;
  const int cl = tid & 127;               // local channel
  const int q = tid >> 7;                 // position quarter (wave-uniform)
  const int sblk = s * (704 * 16);

  const float* xs = x + (size_t)n * NB_STRIDE + (size_t)(chalf * 128) * CH_STRIDE + g * P_;

  const int li0 = tid, li1 = tid + 512;
  const int lc0 = li0 >> 3, lj0 = li0 & 7;
  const int lc1 = li1 >> 3, lj1 = li1 & 7;
  const float* gp0 = xs + (size_t)lc0 * CH_STRIDE + lj0 * 4;
  const float* gp1 = xs + (size_t)lc1 * CH_STRIDE + lj1 * 4;
  const int wo0 = lc0 * 32 + ((lj0 * 4) ^ ((lc0 & 7) * 4));
  const int wo1 = lc1 * 32 + ((lj1 * 4) ^ ((lc1 & 7) * 4));

  const int sw = (cl & 7) * 4;
  const int rbase = cl * 32;

  float acc[16];
  #pragma unroll
  for (int k = 0; k < 16; k++) acc[k] = 0.f;

  float4 r0 = *(const float4*)gp0;
  float4 r1 = *(const float4*)gp1;
  *(float4*)&xl[wo0] = r0;
  *(float4*)&xl[wo1] = r1;
  __syncthreads();

  for (int tt = 0; tt < 22; tt++) {
    const int p0 = tt * 32;
    float4 n0, n1;
    if (tt < 21) {
      n0 = *(const float4*)(gp0 + p0 + 32);
      n1 = *(const float4*)(gp1 + p0 + 32);
    }

    #pragma unroll
    for (int jj = 0; jj < 8; jj += 4) {
      const int pp0 = q * 8 + jj;
      float4 xv = *(const float4*)&xl[rbase + (pp0 ^ sw)];
      float xa[4] = {xv.x, xv.y, xv.z, xv.w};
      #pragma unroll
      for (int dj = 0; dj < 4; dj++) {
        int uofs = __builtin_amdgcn_readfirstlane(sblk + (p0 + pp0 + dj) * 16);
        const float4* sp = (const float4*)(supp_pk + uofs);
        float4 s0 = sp[0], s1 = sp[1], s2 = sp[2], s3 = sp[3];
        float a = xa[dj];
        acc[0]  += a * s0.x; acc[1]  += a * s0.y; acc[2]  += a * s0.z; acc[3]  += a * s0.w;
        acc[4]  += a * s1.x; acc[5]  += a * s1.y; acc[6]  += a * s1.z; acc[7]  += a * s1.w;
        acc[8]  += a * s2.x; acc[9]  += a * s2.y; acc[10] += a * s2.z; acc[11] += a * s2.w;
        acc[12] += a * s3.x; acc[13] += a * s3.y; acc[14] += a * s3.z; acc[15] += a * s3.w;
      }
    }

    __syncthreads();
    if (tt < 21) {
      *(float4*)&xl[wo0] = n0;
      *(float4*)&xl[wo1] = n1;
      __syncthreads();
    }
  }

  // quarter-reduce via LDS (xl reused)
  if (q >= 2) {
    float* dst = &xl[((q - 2) * 128 + cl) * 16];
    #pragma unroll
    for (int kq = 0; kq < 4; kq++)
      ((float4*)dst)[kq] = make_float4(acc[kq*4], acc[kq*4+1], acc[kq*4+2], acc[kq*4+3]);
  }
  __syncthreads();
  if (q < 2) {
    const float* src = &xl[(q * 128 + cl) * 16];
    #pragma unroll
    for (int k = 0; k < 16; k++) acc[k] += src[k];
  }
  __syncthreads();
  if (q == 1) {
    float* dst = &xl[cl * 16];
    #pragma unroll
    for (int kq = 0; kq < 4; kq++)
      ((float4*)dst)[kq] = make_float4(acc[kq*4], acc[kq*4+1], acc[kq*4+2], acc[kq*4+3]);
  }
  __syncthreads();
  if (q == 0) {
    const float* src = &xl[cl * 16];
    float* op = out + ((size_t)(n * 256 + chalf * 128 + cl) * 64) + g * 16;
    #pragma unroll
    for (int kq = 0; kq < 4; kq++) {
      int u = __builtin_amdgcn_readfirstlane(s * 16 + kq * 4);
      const float4 iv = *(const float4*)(invden + u);
      float4 o;
      o.x = (acc[kq*4+0] + src[kq*4+0]) * iv.x;
      o.y = (acc[kq*4+1] + src[kq*4+1]) * iv.y;
      o.z = (acc[kq*4+2] + src[kq*4+2]) * iv.z;
      o.w = (acc[kq*4+3] + src[kq*4+3]) * iv.w;
      ((float4*)op)[kq] = o;
    }
  }
}

// ---------------- kernel D: presence normalization ----------------
__global__ __launch_bounds__(64) void k_pres(const float* __restrict__ presraw,
                                             float* __restrict__ out) {
  const int n = blockIdx.x, t = threadIdx.x;
  float v = presraw[n * 64 + t];
  float ssum = v;
  #pragma unroll
  for (int off = 32; off >= 1; off >>= 1) ssum += __shfl_xor(ssum, off);
  out[1048576 + n * 64 + t] = v / fmaxf(ssum, EPS_);
}

extern "C" void kernel_launch(void* const* d_in, const int* in_sizes, int n_in,
                              void* d_out, int out_size, void* d_ws, size_t ws_size,
                              hipStream_t stream) {
  (void)in_sizes; (void)n_in; (void)out_size; (void)ws_size;
  const float* x  = (const float*)d_in[0];
  const float* lb = (const float*)d_in[1];
  float* out = (float*)d_out;
  float* ws = (float*)d_ws;
  float* lbn_ws     = ws;              // 16384 floats
  float* invden_ws  = ws + 16384;      // 4096
  float* presraw_ws = ws + 20480;      // 4096
  float* supp_kp_ws = ws + 24576;      // 2883584 (rawdot half0)
  float* supp_pk_ws = ws + 2908160;    // 2883584 (rawdot half1, then supp [p][k])
  float* sqpw_ws    = out;             // 720896 floats scratch in tokens region;
                                       // k_tokens fully overwrites it afterwards

  k_norm_basis<<<64, 256, 0, stream>>>(lb, lbn_ws);
  k_route_dot<<<512, 256, 0, stream>>>(x, lbn_ws, supp_kp_ws, supp_pk_ws, sqpw_ws);
  k_route_fin<<<256, 1024, 0, stream>>>(supp_kp_ws, supp_pk_ws, sqpw_ws,
                                        supp_pk_ws, invden_ws, presraw_ws);
  k_tokens<<<512, 512, 0, stream>>>(x, supp_pk_ws, invden_ws, out);
  k_pres<<<64, 64, 0, stream>>>(presraw_ws, out);
}

// Round 9
// 333.118 us; speedup vs baseline: 1.0574x; 1.0574x over previous
//
#include <hip/hip_runtime.h>
#include <cstdint>

// LatentFactorPooling on MI355X.
// x: (64,256,64,44) fp32, basis: (4,16,256) fp32.
// out: tokens (64,256,64) fp32 then pres (64,64) fp32.
//
// Round-12: dot/fin split REVERTED. Ledger audit: round-0 monolith k_route
// (dot+pool+softmax+supp+invden) = 112us measured; the split = dot(~107,
// measured r2) + fin(~25-30) + 52MB partial round-trip. The split was never
// a win; the only real win was the fused topk (round 5, -25us). This version
// = round-0 monolith + round-5 topk fusion + DPP/scalar-basis inner loop
// (verified in rounds 3-8).
//
// Workspace layout (floats):
//   lbn_ws     [0,16384)             normalized basis, [g][c][k]
//   invden_ws  [16384,20480)         1/max(sum_p supp,1e-6) per (s,k)
//   presraw    [20480,24576)         unnormalized presence per (s,k)
//   supp_pk    [2908160,5791744)     supp, [s][p][k]  (tokens kernel)

#define C_ 256
#define W_ 44
#define P_ 704          // 16*44 positions per stripe
#define CH_STRIDE 2816  // 64*44
#define NB_STRIDE 720896 // 256*2816
#define TOPK_ 88
#define GATE_ 0.05f
#define EPS_ 1e-6f

// DPP wave-wide shifts: lane i <- lane i-1 (shr) / i+1 (shl), bound_ctrl
// zero-fills the edge lane. VALU pipe.
#define DPP_WAVE_SHL1 0x130
#define DPP_WAVE_SHR1 0x138
__device__ __forceinline__ float dpp_from_left(float v) {   // lane l gets v[l-1], lane0 -> 0
  return __int_as_float(__builtin_amdgcn_update_dpp(
      0, __float_as_int(v), DPP_WAVE_SHR1, 0xF, 0xF, true));
}
__device__ __forceinline__ float dpp_from_right(float v) {  // lane l gets v[l+1], lane63 -> 0
  return __int_as_float(__builtin_amdgcn_update_dpp(
      0, __float_as_int(v), DPP_WAVE_SHL1, 0xF, 0xF, true));
}

// ---------------- kernel A: normalize latent basis ----------------
__global__ __launch_bounds__(256) void k_norm_basis(const float* __restrict__ lb,
                                                    float* __restrict__ lbn) {
  int gk = blockIdx.x;           // g*16+k
  int t = threadIdx.x;           // channel
  float v = lb[gk * 256 + t];
  float ss = v * v;
  #pragma unroll
  for (int off = 32; off >= 1; off >>= 1) ss += __shfl_xor(ss, off);
  __shared__ float red[4];
  if ((t & 63) == 0) red[t >> 6] = ss;
  __syncthreads();
  float tot = red[0] + red[1] + red[2] + red[3];
  float scale = 1.f / fmaxf(sqrtf(tot), 1e-12f);
  int g = gk >> 4, k = gk & 15;
  lbn[((g * 256 + t) << 4) + k] = v * scale;   // [g][c][k]
}

// ---------------- kernel B: MONOLITH routing ----------------
// One block per stripe, 1024 threads, wave w = stripe row w, lanes 0..43
// active. Main loop: barrier-free, LDS-free (DPP horizontal exchange,
// basis via wave-uniform scalar loads), 2-deep ping-pong prefetch.
// Epilogue: 3x3 pool via LDS (linearity), energy gate, softmax, supp,
// invden, then fused exact top-88 per-wave radix select.
#define LOAD_GRP(Pm, P0, Pp, cbase)                                    \
  { _Pragma("unroll")                                                  \
    for (int j_ = 0; j_ < 4; j_++) {                                   \
      const size_t o_ = (size_t)((cbase) + j_) * CH_STRIDE;            \
      Pm[j_] = xm[o_]; P0[j_] = xb[o_]; Pp[j_] = xp[o_];               \
    } }

#define CONS_GRP(Pm, P0, Pp, cbase)                                    \
  { _Pragma("unroll")                                                  \
    for (int j_ = 0; j_ < 4; j_++) {                                   \
      float a  = act ? P0[j_] : 0.f;                                   \
      float am_ = (act && hm) ? Pm[j_] : 0.f;                          \
      float ap_ = (act && hp) ? Pp[j_] : 0.f;                          \
      float vs = am_ + a + ap_;                                        \
      float lf = dpp_from_left(vs);                                    \
      float rt = dpp_from_right(vs);                                   \
      float win = lf + vs + rt;                                        \
      pw2 = fmaf(win, win, pw2);                                       \
      sq  = fmaf(a, a, sq);                                            \
      const int co_ = __builtin_amdgcn_readfirstlane(((cbase) + j_) << 4); \
      const float4* wp4 = (const float4*)(lbb + co_);                  \
      float4 w0 = wp4[0], w1 = wp4[1], w2 = wp4[2], w3 = wp4[3];       \
      rawdot[0]  = fmaf(a, w0.x, rawdot[0]);  rawdot[1]  = fmaf(a, w0.y, rawdot[1]);  \
      rawdot[2]  = fmaf(a, w0.z, rawdot[2]);  rawdot[3]  = fmaf(a, w0.w, rawdot[3]);  \
      rawdot[4]  = fmaf(a, w1.x, rawdot[4]);  rawdot[5]  = fmaf(a, w1.y, rawdot[5]);  \
      rawdot[6]  = fmaf(a, w1.z, rawdot[6]);  rawdot[7]  = fmaf(a, w1.w, rawdot[7]);  \
      rawdot[8]  = fmaf(a, w2.x, rawdot[8]);  rawdot[9]  = fmaf(a, w2.y, rawdot[9]);  \
      rawdot[10] = fmaf(a, w2.z, rawdot[10]); rawdot[11] = fmaf(a, w2.w, rawdot[11]); \
      rawdot[12] = fmaf(a, w3.x, rawdot[12]); rawdot[13] = fmaf(a, w3.y, rawdot[13]); \
      rawdot[14] = fmaf(a, w3.z, rawdot[14]); rawdot[15] = fmaf(a, w3.w, rawdot[15]); \
    } }

__global__ __launch_bounds__(1024, 4) void k_route(const float* __restrict__ x,
                                                   const float* __restrict__ lbn,
                                                   float* __restrict__ supp_pk,
                                                   float* __restrict__ invden_ws,
                                                   float* __restrict__ presraw) {
  __shared__ float rsl[11264];          // rawdot [k][704], then supp [k][704]; 44 KB
  __shared__ uint32_t hist_l[16 * 256]; // per-wave radix histograms, 16 KB
  __shared__ float redA[16];
  __shared__ float redB[16];
  __shared__ float redM[2];
  __shared__ float red2[16 * 16];

  const int tid = threadIdx.x;
  const int w = tid >> 6;          // row
  const int l = tid & 63;          // col
  const bool act = (l < 44);
  const int s = blockIdx.x, n = s >> 2, g = s & 3;
  const int p = w * 44 + l;

  const int lsafe = act ? l : 0;   // address clamp
  const float* xb = x + (size_t)n * NB_STRIDE + (g * 16 + w) * 44 + lsafe;
  const float* xm = xb + ((w > 0)  ? -44 : 0);   // clamped row addresses
  const float* xp = xb + ((w < 15) ?  44 : 0);
  const bool hm = (w > 0), hp = (w < 15);

  // wave-uniform basis base for this group: 256ch x 16k slice
  const float* lbb = lbn + (g << 12);

  float rawdot[16];
  #pragma unroll
  for (int k = 0; k < 16; k++) rawdot[k] = 0.f;
  float sq = 0.f, pw2 = 0.f;

  float Avm[4], Av0[4], Avp[4];
  float Bvm[4], Bv0[4], Bvp[4];

  LOAD_GRP(Avm, Av0, Avp, 0)
  for (int c = 0; c < 256; c += 8) {
    LOAD_GRP(Bvm, Bv0, Bvp, c + 4)
    CONS_GRP(Avm, Av0, Avp, c)
    if (c + 8 < 256) { LOAD_GRP(Avm, Av0, Avp, c + 8) }
    CONS_GRP(Bvm, Bv0, Bvp, c + 4)
  }

  // ---- epilogue: pool, gate, softmax, supp, invden, fused topk ----
  if (act) {
    #pragma unroll
    for (int k = 0; k < 16; k++) rsl[k * 704 + p] = rawdot[k];
  }
  __syncthreads();   // rsl ready

  // 3x3 pool of rawdot (linearity: pool(raw).basis == pool(raw.basis))
  float pd[16];
  #pragma unroll
  for (int k = 0; k < 16; k++) pd[k] = 0.f;
  if (act) {
    #pragma unroll
    for (int dy = -1; dy <= 1; dy++) {
      int yy = w + dy;
      if (yy < 0 || yy > 15) continue;
      #pragma unroll
      for (int dx = -1; dx <= 1; dx++) {
        int xx = l + dx;
        if (xx < 0 || xx > 43) continue;
        int pp = yy * 44 + xx;
        #pragma unroll
        for (int k = 0; k < 16; k++) pd[k] += rsl[k * 704 + pp];
      }
    }
  }

  // stripe-wide energy max
  float e_raw = sq * (1.f / 256.f);            // inactive lanes: 0
  float m = e_raw;
  #pragma unroll
  for (int off = 32; off >= 1; off >>= 1) m = fmaxf(m, __shfl_xor(m, off));
  if (l == 0) redA[w] = m;
  __syncthreads();                             // (also: all rsl pool-reads done)
  if (tid == 0) {
    float mm = redA[0];
    for (int w2 = 1; w2 < 16; w2++) mm = fmaxf(mm, redA[w2]);
    redM[0] = mm;
  }
  __syncthreads();
  float M = fmaxf(redM[0], EPS_);
  float e = e_raw / M;
  float am = (e > GATE_) ? 1.f : 0.f;
  float fb = (e_raw > 0.f) ? 1.f : 0.f;
  float a = am;
  #pragma unroll
  for (int off = 32; off >= 1; off >>= 1) a += __shfl_xor(a, off);
  if (l == 0) redB[w] = a;
  __syncthreads();
  if (tid == 0) {
    float sm = 0.f;
    for (int w2 = 0; w2 < 16; w2++) sm += redB[w2];
    redM[1] = sm;
  }
  __syncthreads();
  if (redM[1] <= 0.f) am = fb;

  float pnorm = sqrtf(pw2) * (1.f / 9.f);      // ||pooled||
  float invn = 1.f / fmaxf(pnorm, 1e-12f);
  float scl = invn * (8.f / 9.f);              // /9 pool, /0.125 temp
  float li[16];
  float mx = -1e30f;
  #pragma unroll
  for (int k = 0; k < 16; k++) { li[k] = pd[k] * scl; mx = fmaxf(mx, li[k]); }
  float ssum = 0.f;
  #pragma unroll
  for (int k = 0; k < 16; k++) { li[k] = __expf(li[k] - mx); ssum += li[k]; }
  float rs2 = am / ssum;
  float supp[16];
  #pragma unroll
  for (int k = 0; k < 16; k++) supp[k] = li[k] * rs2;

  // global supp in [p][k] layout for k_tokens
  if (act) {
    float* spk = supp_pk + ((size_t)s * 704 + p) * 16;
    #pragma unroll
    for (int kq = 0; kq < 4; kq++)
      ((float4*)spk)[kq] = make_float4(supp[kq*4+0], supp[kq*4+1],
                                       supp[kq*4+2], supp[kq*4+3]);
  }

  // per-k denominators (inactive lanes contribute 0)
  #pragma unroll
  for (int k = 0; k < 16; k++) {
    float v2 = act ? supp[k] : 0.f;
    #pragma unroll
    for (int off = 32; off >= 1; off >>= 1) v2 += __shfl_xor(v2, off);
    if (l == 0) red2[w * 16 + k] = v2;
  }
  __syncthreads();
  if (tid < 16) {
    float den = 0.f;
    for (int w2 = 0; w2 < 16; w2++) den += red2[w2 * 16 + tid];
    invden_ws[s * 16 + tid] = 1.f / fmaxf(den, EPS_);
  }

  // ---- fused exact top-88 mean (per-wave radix select) ----
  // overwrite rsl with supp [k][704] (all pool reads completed before the
  // redA barrier above)
  if (act) {
    #pragma unroll
    for (int k = 0; k < 16; k++) rsl[k * 704 + p] = supp[k];
  }
  __syncthreads();   // supp in LDS visible to all waves

  {
    const int k = w;               // wave w owns latent k
    uint32_t key[11];
    #pragma unroll
    for (int j = 0; j < 11; j++)
      key[j] = __float_as_uint(rsl[k * 704 + l + 64 * j]);  // supp>=0 -> monotone bits
    uint32_t* h = &hist_l[w * 256];
    uint32_t prefix = 0, remaining = TOPK_;
    #pragma unroll
    for (int b = 3; b >= 0; b--) {
      const int shift = b * 8;
      *(uint4*)&h[l * 4] = make_uint4(0u, 0u, 0u, 0u);
      uint32_t mhi = (b == 3) ? 0u : (0xFFFFFFFFu << (shift + 8));
      #pragma unroll
      for (int j = 0; j < 11; j++)
        if ((key[j] & mhi) == (prefix & mhi))
          atomicAdd(&h[(key[j] >> shift) & 255u], 1u);
      uint4 bn = *(uint4*)&h[l * 4];
      uint32_t T = bn.x + bn.y + bn.z + bn.w;
      uint32_t inc = T;
      #pragma unroll
      for (int off = 1; off < 64; off <<= 1) {
        uint32_t o = (uint32_t)__shfl_down((int)inc, off);
        if (l + off < 64) inc += o;
      }                              // inc = sum over lanes >= l
      uint32_t excl = inc - T;       // lanes > l
      uint32_t g3 = excl + bn.w, g2 = g3 + bn.z, g1 = g2 + bn.y, g0 = g1 + bn.x;
      uint32_t pk = 0u;
      if (g0 >= remaining && g1 < remaining) pk = ((uint32_t)(4*l+0) << 16) | (remaining - g1);
      if (g1 >= remaining && g2 < remaining) pk = ((uint32_t)(4*l+1) << 16) | (remaining - g2);
      if (g2 >= remaining && g3 < remaining) pk = ((uint32_t)(4*l+2) << 16) | (remaining - g3);
      if (g3 >= remaining && excl < remaining) pk = ((uint32_t)(4*l+3) << 16) | (remaining - excl);
      #pragma unroll
      for (int off = 32; off >= 1; off >>= 1) pk |= (uint32_t)__shfl_xor((int)pk, off);
      prefix |= ((pk >> 16) & 255u) << shift;
      remaining = pk & 0xFFFFu;
    }
    float tf = __uint_as_float(prefix);
    float sgt = 0.f; uint32_t cgt = 0u;
    #pragma unroll
    for (int j = 0; j < 11; j++)
      if (key[j] > prefix) { sgt += __uint_as_float(key[j]); cgt++; }
    #pragma unroll
    for (int off = 32; off >= 1; off >>= 1) {
      sgt += __shfl_xor(sgt, off);
      cgt += (uint32_t)__shfl_xor((int)cgt, off);
    }
    if (l == 0)
      presraw[s * 16 + k] = (sgt + (float)(TOPK_ - cgt) * tf) * (1.f / (float)TOPK_);
  }
}

// ---------------- kernel 3: tokens GEMM, channel-split (2 blocks/stripe) ----------------
__global__ __launch_bounds__(512, 4) void k_tokens(const float* __restrict__ x,
                                                   const float* __restrict__ supp_pk,
                                                   const float* __restrict__ invden,
                                                   float* __restrict__ out) {
  __shared__ float xl[4096];   // 128ch x 32pos; reused for quarter-reduce
  const int tid = threadIdx.x;
  const int bid = blockIdx.x;
  const int s = bid >> 1, chalf = bid & 1;
  const int n = s >> 2, g = s & 3;
  const int cl = tid & 127;               // local channel
  const int q = tid >> 7;                 // position quarter (wave-uniform)
  const int sblk = s * (704 * 16);

  const float* xs = x + (size_t)n * NB_STRIDE + (size_t)(chalf * 128) * CH_STRIDE + g * P_;

  const int li0 = tid, li1 = tid + 512;
  const int lc0 = li0 >> 3, lj0 = li0 & 7;
  const int lc1 = li1 >> 3, lj1 = li1 & 7;
  const float* gp0 = xs + (size_t)lc0 * CH_STRIDE + lj0 * 4;
  const float* gp1 = xs + (size_t)lc1 * CH_STRIDE + lj1 * 4;
  const int wo0 = lc0 * 32 + ((lj0 * 4) ^ ((lc0 & 7) * 4));
  const int wo1 = lc1 * 32 + ((lj1 * 4) ^ ((lc1 & 7) * 4));

  const int sw = (cl & 7) * 4;
  const int rbase = cl * 32;

  float acc[16];
  #pragma unroll
  for (int k = 0; k < 16; k++) acc[k] = 0.f;

  float4 r0 = *(const float4*)gp0;
  float4 r1 = *(const float4*)gp1;
  *(float4*)&xl[wo0] = r0;
  *(float4*)&xl[wo1] = r1;
  __syncthreads();

  for (int tt = 0; tt < 22; tt++) {
    const int p0 = tt * 32;
    float4 n0, n1;
    if (tt < 21) {
      n0 = *(const float4*)(gp0 + p0 + 32);
      n1 = *(const float4*)(gp1 + p0 + 32);
    }

    #pragma unroll
    for (int jj = 0; jj < 8; jj += 4) {
      const int pp0 = q * 8 + jj;
      float4 xv = *(const float4*)&xl[rbase + (pp0 ^ sw)];
      float xa[4] = {xv.x, xv.y, xv.z, xv.w};
      #pragma unroll
      for (int dj = 0; dj < 4; dj++) {
        int uofs = __builtin_amdgcn_readfirstlane(sblk + (p0 + pp0 + dj) * 16);
        const float4* sp = (const float4*)(supp_pk + uofs);
        float4 s0 = sp[0], s1 = sp[1], s2 = sp[2], s3 = sp[3];
        float a = xa[dj];
        acc[0]  += a * s0.x; acc[1]  += a * s0.y; acc[2]  += a * s0.z; acc[3]  += a * s0.w;
        acc[4]  += a * s1.x; acc[5]  += a * s1.y; acc[6]  += a * s1.z; acc[7]  += a * s1.w;
        acc[8]  += a * s2.x; acc[9]  += a * s2.y; acc[10] += a * s2.z; acc[11] += a * s2.w;
        acc[12] += a * s3.x; acc[13] += a * s3.y; acc[14] += a * s3.z; acc[15] += a * s3.w;
      }
    }

    __syncthreads();
    if (tt < 21) {
      *(float4*)&xl[wo0] = n0;
      *(float4*)&xl[wo1] = n1;
      __syncthreads();
    }
  }

  // quarter-reduce via LDS (xl reused)
  if (q >= 2) {
    float* dst = &xl[((q - 2) * 128 + cl) * 16];
    #pragma unroll
    for (int kq = 0; kq < 4; kq++)
      ((float4*)dst)[kq] = make_float4(acc[kq*4], acc[kq*4+1], acc[kq*4+2], acc[kq*4+3]);
  }
  __syncthreads();
  if (q < 2) {
    const float* src = &xl[(q * 128 + cl) * 16];
    #pragma unroll
    for (int k = 0; k < 16; k++) acc[k] += src[k];
  }
  __syncthreads();
  if (q == 1) {
    float* dst = &xl[cl * 16];
    #pragma unroll
    for (int kq = 0; kq < 4; kq++)
      ((float4*)dst)[kq] = make_float4(acc[kq*4], acc[kq*4+1], acc[kq*4+2], acc[kq*4+3]);
  }
  __syncthreads();
  if (q == 0) {
    const float* src = &xl[cl * 16];
    float* op = out + ((size_t)(n * 256 + chalf * 128 + cl) * 64) + g * 16;
    #pragma unroll
    for (int kq = 0; kq < 4; kq++) {
      int u = __builtin_amdgcn_readfirstlane(s * 16 + kq * 4);
      const float4 iv = *(const float4*)(invden + u);
      float4 o;
      o.x = (acc[kq*4+0] + src[kq*4+0]) * iv.x;
      o.y = (acc[kq*4+1] + src[kq*4+1]) * iv.y;
      o.z = (acc[kq*4+2] + src[kq*4+2]) * iv.z;
      o.w = (acc[kq*4+3] + src[kq*4+3]) * iv.w;
      ((float4*)op)[kq] = o;
    }
  }
}

// ---------------- kernel D: presence normalization ----------------
__global__ __launch_bounds__(64) void k_pres(const float* __restrict__ presraw,
                                             float* __restrict__ out) {
  const int n = blockIdx.x, t = threadIdx.x;
  float v = presraw[n * 64 + t];
  float ssum = v;
  #pragma unroll
  for (int off = 32; off >= 1; off >>= 1) ssum += __shfl_xor(ssum, off);
  out[1048576 + n * 64 + t] = v / fmaxf(ssum, EPS_);
}

extern "C" void kernel_launch(void* const* d_in, const int* in_sizes, int n_in,
                              void* d_out, int out_size, void* d_ws, size_t ws_size,
                              hipStream_t stream) {
  (void)in_sizes; (void)n_in; (void)out_size; (void)ws_size;
  const float* x  = (const float*)d_in[0];
  const float* lb = (const float*)d_in[1];
  float* out = (float*)d_out;
  float* ws = (float*)d_ws;
  float* lbn_ws     = ws;              // 16384 floats
  float* invden_ws  = ws + 16384;      // 4096
  float* presraw_ws = ws + 20480;      // 4096
  float* supp_pk_ws = ws + 2908160;    // 2883584, supp [s][p][k]

  k_norm_basis<<<64, 256, 0, stream>>>(lb, lbn_ws);
  k_route<<<256, 1024, 0, stream>>>(x, lbn_ws, supp_pk_ws, invden_ws, presraw_ws);
  k_tokens<<<512, 512, 0, stream>>>(x, supp_pk_ws, invden_ws, out);
  k_pres<<<64, 64, 0, stream>>>(presraw_ws, out);
}